// Round 2
// baseline (456.354 us; speedup 1.0000x reference)
//
#include <hip/hip_runtime.h>
#include <stdint.h>

#define NUM_TOKENS 16384
#define DIM        4096
#define NEXP       256
#define MB         32      // tokens per block
#define BK         64      // K per staging step
#define NITER      (DIM / BK)
#define APAD       72      // A row stride (+8 kills bank conflicts, keeps 16B align)
#define NWAVES     8
#define MARGIN     0.025f  // ~8.6 sigma of the pure-bf16 gap error (std ~2.9e-3)
#define CAP        16384   // refinement list capacity

typedef __attribute__((ext_vector_type(4))) float   f32x4;
typedef __attribute__((ext_vector_type(8))) __bf16  bf16x8;

static __device__ __forceinline__ unsigned short f32_to_bf16(float f) {
    unsigned int u = __float_as_uint(f);
    u += 0x7fffu + ((u >> 16) & 1u);     // round-to-nearest-even
    return (unsigned short)(u >> 16);
}

// ---------------------------------------------------------------- kernel 1
// Convert weight fp32 -> bf16; zero the refinement counter.
__global__ void cvt_weights(const float* __restrict__ w,
                            unsigned short* __restrict__ wh,
                            int* __restrict__ counter) {
    if (blockIdx.x == 0 && threadIdx.x == 0) *counter = 0;
    const int n4 = NEXP * DIM / 4;
    const int stride = gridDim.x * blockDim.x;
    for (int i = blockIdx.x * blockDim.x + threadIdx.x; i < n4; i += stride) {
        float4 v = ((const float4*)w)[i];
        ushort4 h;
        h.x = f32_to_bf16(v.x); h.y = f32_to_bf16(v.y);
        h.z = f32_to_bf16(v.z); h.w = f32_to_bf16(v.w);
        ((ushort4*)wh)[i] = h;
    }
}

// ---------------------------------------------------------------- kernel 2
// Fused bf16 GEMM + top-2: block = 32 tokens x 256 experts, full K.
// 512 thr / 8 waves; wave = 32 tokens x 32 experts (mt=2, nt=2).
//
// R2 change: B (weights, 2 MB bf16 = L2-resident) no longer goes through
// LDS at all. Each lane loads its MFMA B-fragment (16 B at e*DIM+k)
// straight into VGPRs, refilled for iter it+1 right after the MFMAs that
// consume iter it's copy (~400 cyc prefetch lead covers L2 latency).
// Rationale (post-mortem of the neutral R1 pipeline change): the LDS pipe
// was the largest per-iter term (~2000 cyc/CU-iter: B DMA-write 512 +
// B reads 770 + A reads 770) vs HBM x-stream 1600 and MFMA 620. Removing
// the B round-trip cuts LDS traffic ~3x, kills all DMA instructions and
// the DMA->barrier coupling, and drops LDS 77.5 KB -> 13.3 KB.
// A stays in LDS (converted once, read by all 8 waves), double-buffered
// with ONE raw barrier per iter (lgkmcnt-only wait: no vmem drain, so the
// x/B prefetch streams stay in flight across barriers). x prefetch 2-deep.
__global__ __launch_bounds__(512, 4) void gate_main(
    const float* __restrict__ x,
    const unsigned short* __restrict__ wh,
    float* __restrict__ out,           // [0,T) weights, [T,2T) indices (as float)
    int* __restrict__ counter,
    int4* __restrict__ entries)
{
    __shared__ unsigned short lAh[2][MB][APAD];    // 2 x 4.5 KB
    __shared__ float4 cand[NWAVES][MB];            // 4 KB

    const int tid  = threadIdx.x;
    const int wv   = tid >> 6;          // wave 0..7 -> experts [wv*32, wv*32+32)
    const int lane = tid & 63;
    const int tok0 = blockIdx.x * MB;

    // A staging: thread covers token ta, 4 floats at kcol
    const int ta   = tid >> 4;          // 0..31
    const int kcol = (tid & 15) * 4;    // 0..60
    const float* xrow = x + (size_t)(tok0 + ta) * DIM + kcol;

    const int quad = lane >> 4;
    const int col  = lane & 15;

    // per-lane B fragment pointers: expert e = wv*32 + nt*16 + col, k base quad*8.
    // Per instruction: 16 experts x 64 B contiguous (4 quads) = sector-aligned.
    const unsigned short* bp[2];
    #pragma unroll
    for (int nt = 0; nt < 2; ++nt)
        bp[nt] = wh + (size_t)(wv * 32 + nt * 16 + col) * DIM + quad * 8;

    f32x4 acc[2][2];
    #pragma unroll
    for (int mt = 0; mt < 2; ++mt)
        #pragma unroll
        for (int nt = 0; nt < 2; ++nt)
            acc[mt][nt] = f32x4{0.f, 0.f, 0.f, 0.f};

    bf16x8 b[2][2];    // [kk2][nt] current-iter B fragments (static idx only)

    // ---- prologue: x(0), x(1) in regs; B(0) in regs; stage A(0); prefetch x(2).
    float4 xva = *(const float4*)(xrow);             // x(0)
    float4 xvb = *(const float4*)(xrow + BK);        // x(1)
    #pragma unroll
    for (int kk2 = 0; kk2 < 2; ++kk2)
        #pragma unroll
        for (int nt = 0; nt < 2; ++nt)
            b[kk2][nt] = *(const bf16x8*)(bp[nt] + kk2 * 32);
    {
        ushort4 h;
        h.x = f32_to_bf16(xva.x); h.y = f32_to_bf16(xva.y);
        h.z = f32_to_bf16(xva.z); h.w = f32_to_bf16(xva.w);
        *(ushort4*)&lAh[0][ta][kcol] = h;
    }
    xva = *(const float4*)(xrow + 2 * BK);           // x(2)

    asm volatile("s_waitcnt lgkmcnt(0)" ::: "memory");
    __builtin_amdgcn_s_barrier();
    asm volatile("" ::: "memory");

    // One iteration: stage A(it+1) into buf cur^1, compute(it) from buf cur,
    // refill b[] with B(it+1) right after use, single end-of-iter barrier.
    // Buffer safety with ONE barrier: writes in interval k touch buf (k+1)&1,
    // reads touch buf k&1; barrier k+1 separates interval k writes from
    // interval k+1 reads of the same buffer.
    auto iter_body = [&](int it, int cur, float4& xcons) {
        const int nxt = cur ^ 1;
        if (it + 1 < NITER) {
            ushort4 h;
            h.x = f32_to_bf16(xcons.x); h.y = f32_to_bf16(xcons.y);
            h.z = f32_to_bf16(xcons.z); h.w = f32_to_bf16(xcons.w);
            *(ushort4*)&lAh[nxt][ta][kcol] = h;
            if (it + 3 < NITER)
                xcons = *(const float4*)(xrow + (it + 3) * BK);
        }
        #pragma unroll
        for (int kk2 = 0; kk2 < 2; ++kk2) {
            bf16x8 ah0 = *(const bf16x8*)&lAh[cur][col][kk2 * 32 + quad * 8];
            bf16x8 ah1 = *(const bf16x8*)&lAh[cur][16 + col][kk2 * 32 + quad * 8];
            acc[0][0] = __builtin_amdgcn_mfma_f32_16x16x32_bf16(ah0, b[kk2][0], acc[0][0], 0, 0, 0);
            acc[1][0] = __builtin_amdgcn_mfma_f32_16x16x32_bf16(ah1, b[kk2][0], acc[1][0], 0, 0, 0);
            acc[0][1] = __builtin_amdgcn_mfma_f32_16x16x32_bf16(ah0, b[kk2][1], acc[0][1], 0, 0, 0);
            acc[1][1] = __builtin_amdgcn_mfma_f32_16x16x32_bf16(ah1, b[kk2][1], acc[1][1], 0, 0, 0);
            if (it + 1 < NITER) {       // refill after use: ~400cy lead into it+1
                #pragma unroll
                for (int nt = 0; nt < 2; ++nt)
                    b[kk2][nt] = *(const bf16x8*)(bp[nt] + (it + 1) * BK + kk2 * 32);
            }
        }
        asm volatile("s_waitcnt lgkmcnt(0)" ::: "memory");  // publish A(it+1) writes
        __builtin_amdgcn_s_barrier();
        asm volatile("" ::: "memory");
    };

    #pragma unroll 1
    for (int itp = 0; itp < NITER; itp += 2) {
        iter_body(itp,     0, xvb);   // even it consumes x(it+1) from xvb
        iter_body(itp + 1, 1, xva);   // odd  it consumes x(it+1) from xva
    }

    // ---- epilogue: per-wave top-2 over its 32 experts, per token.
    // C/D layout (16x16): col = lane&15 (expert), row = quad*4 + reg (token).
    #pragma unroll
    for (int mt = 0; mt < 2; ++mt) {
        #pragma unroll
        for (int r = 0; r < 4; ++r) {
            float s0 = acc[mt][0][r]; int e0 = wv * 32 + col;
            float s1 = acc[mt][1][r]; int e1 = e0 + 16;
            float t1s, t2s; int t1e, t2e;
            if (s1 > s0) { t1s = s1; t1e = e1; t2s = s0; t2e = e0; }
            else         { t1s = s0; t1e = e0; t2s = s1; t2e = e1; }
            #pragma unroll
            for (int m = 1; m <= 8; m <<= 1) {
                float o1s = __shfl_xor(t1s, m); int o1e = __shfl_xor(t1e, m);
                float o2s = __shfl_xor(t2s, m); int o2e = __shfl_xor(t2e, m);
                bool o1_top = (o1s > t1s) || (o1s == t1s && o1e < t1e);
                if (o1_top) {
                    bool keep_t1 = (t1s > o2s) || (t1s == o2s && t1e < o2e);
                    t2s = keep_t1 ? t1s : o2s; t2e = keep_t1 ? t1e : o2e;
                    t1s = o1s; t1e = o1e;
                } else {
                    bool o1_2nd = (o1s > t2s) || (o1s == t2s && o1e < t2e);
                    if (o1_2nd) { t2s = o1s; t2e = o1e; }
                }
            }
            if (col == 0) {
                int tok = mt * 16 + quad * 4 + r;
                cand[wv][tok] = make_float4(t1s, __int_as_float(t1e), t2s, __int_as_float(t2e));
            }
        }
    }
    __syncthreads();

    // ---- final merge across waves; write outputs + near-tie flags
    if (tid < MB) {
        float4 c0 = cand[0][tid];
        float t1s = c0.x; int t1e = __float_as_int(c0.y);
        float t2s = c0.z; int t2e = __float_as_int(c0.w);
        #pragma unroll
        for (int wvi = 1; wvi < NWAVES; ++wvi) {
            float4 c = cand[wvi][tid];
            float o1s = c.x; int o1e = __float_as_int(c.y);
            float o2s = c.z; int o2e = __float_as_int(c.w);
            bool o1_top = (o1s > t1s) || (o1s == t1s && o1e < t1e);
            if (o1_top) {
                bool keep_t1 = (t1s > o2s) || (t1s == o2s && t1e < o2e);
                t2s = keep_t1 ? t1s : o2s; t2e = keep_t1 ? t1e : o2e;
                t1s = o1s; t1e = o1e;
            } else {
                bool o1_2nd = (o1s > t2s) || (o1s == t2s && o1e < t2e);
                if (o1_2nd) { t2s = o1s; t2e = o1e; }
            }
        }
        const int gtok = tok0 + tid;
        out[gtok] = 1.0f;                       // STE forward value at argmax
        out[NUM_TOKENS + gtok] = (float)t1e;    // index as float
        if (t1s - t2s < MARGIN) {
            int slot = atomicAdd(counter, 1);
            if (slot < CAP) entries[slot] = make_int4(gtok, t1e, t2e, 0);
        }
    }
}

// ---------------------------------------------------------------- kernel 3
// fp64 re-verification of near-tie tokens (one wave per flagged token).
__global__ void refine(const float* __restrict__ x,
                       const float* __restrict__ w,
                       const int* __restrict__ counter,
                       const int4* __restrict__ entries,
                       float* __restrict__ out) {
    const int gwave  = (blockIdx.x * blockDim.x + threadIdx.x) >> 6;
    const int lane   = threadIdx.x & 63;
    const int nwaves = (gridDim.x * blockDim.x) >> 6;
    int n = *counter; if (n > CAP) n = CAP;
    for (int i = gwave; i < n; i += nwaves) {
        int4 e = entries[i];
        const float* xr = x + (size_t)e.x * DIM;
        const float* w1 = w + (size_t)e.y * DIM;
        const float* w2 = w + (size_t)e.z * DIM;
        double d1 = 0.0, d2 = 0.0;
        for (int k = lane; k < DIM; k += 64) {
            double xv = (double)xr[k];
            d1 += xv * (double)w1[k];
            d2 += xv * (double)w2[k];
        }
        #pragma unroll
        for (int m = 32; m > 0; m >>= 1) {
            d1 += __shfl_xor(d1, m);
            d2 += __shfl_xor(d2, m);
        }
        if (lane == 0) {
            int best = (d1 > d2) ? e.y : ((d2 > d1) ? e.z : (e.y < e.z ? e.y : e.z));
            out[NUM_TOKENS + e.x] = (float)best;
        }
    }
}

// ---------------------------------------------------------------- launcher
extern "C" void kernel_launch(void* const* d_in, const int* in_sizes, int n_in,
                              void* d_out, int out_size, void* d_ws, size_t ws_size,
                              hipStream_t stream) {
    const float* x = (const float*)d_in[0];
    const float* w = (const float*)d_in[1];
    float* out = (float*)d_out;

    char* ws = (char*)d_ws;
    unsigned short* wh = (unsigned short*)ws;                     // 2 MB
    int*  counter = (int*)(ws + (2u << 20));
    int4* entries = (int4*)(ws + (2u << 20) + 16);                // 256 KB

    cvt_weights<<<256, 256, 0, stream>>>(w, wh, counter);
    gate_main<<<NUM_TOKENS / MB, 512, 0, stream>>>(x, wh, out, counter, entries);
    refine<<<256, 256, 0, stream>>>(x, w, counter, entries, out);
}